// Round 3
// baseline (1512.081 us; speedup 1.0000x reference)
//
#include <hip/hip_runtime.h>

#define N_NODES 100000
#define N_EDGES 1600000
#define IN_F 32
#define OUT_F 64
#define K_TOTAL 25          // 5x5
#define CAP 64              // bucket capacity; Poisson(16) max over 100K nodes ~45

// ---- bucket-tier workspace layout (bytes) ----
// cnt : int[100000]          @ 0          (400000 B)
// WT  : float[64*800]        @ 400000     (204800 B)  W transposed
// ids : int[100000*64]       @ 604800     (25600000 B)
#define WSB_CNT 0
#define WSB_WT  400000
#define WSB_IDS 604800
#define WSB_NEED (604800 + (size_t)N_NODES * CAP * 4)   // 26,204,800

// ---- legacy CSR-tier workspace layout (fallback) ----
#define WS_CNT    0
#define WS_OFFS   400000
#define WS_CURSOR 800000
#define WS_TSUMS  1200000
#define WS_TBASE  1200512
#define WS_PAYLOAD 1201024
#define N_TILES 98

// degree-1 B-spline basis: 4 corners (2D), kernel 5x5
__device__ __forceinline__ void basis_from(float p0, float p1, float b[4], int k[4]) {
    float v0 = p0 * 4.0f;
    float v1 = p1 * 4.0f;
    int i0 = (int)floorf(v0); i0 = min(max(i0, 0), 3);
    int i1 = (int)floorf(v1); i1 = min(max(i1, 0), 3);
    float f0 = v0 - (float)i0;
    float f1 = v1 - (float)i1;
    float a00 = 1.0f - f0, a01 = f0;
    float a10 = 1.0f - f1, a11 = f1;
    b[0] = a00 * a10; k[0] = (i0 + 0) * 5 + (i1 + 0);
    b[1] = a00 * a11; k[1] = (i0 + 0) * 5 + (i1 + 1);
    b[2] = a01 * a10; k[2] = (i0 + 1) * 5 + (i1 + 0);
    b[3] = a01 * a11; k[3] = (i0 + 1) * 5 + (i1 + 1);
}

// =================== bucket tier ===================

__global__ __launch_bounds__(256) void transpose_w(const float* __restrict__ W,
                                                   float* __restrict__ WT) {
    int idx = blockIdx.x * 256 + threadIdx.x;          // grid covers 51200 exactly
    int j = idx >> 6, o = idx & 63;
    WT[o * 800 + j] = W[idx];
}

__global__ __launch_bounds__(256) void fill_bucket(const int* __restrict__ ei,
                                                   int* __restrict__ cnt,
                                                   int* __restrict__ ids) {
    int e = blockIdx.x * 256 + threadIdx.x;            // grid covers N_EDGES exactly
    int row = ei[e];
    int pos = atomicAdd(&cnt[row], 1);
    if (pos < CAP) ids[row * CAP + pos] = e;
}

// block = 256 threads, 8 nodes. LDS H[8][800] = 25.6 KB.
// Accumulate: 32 threads/node (nn=t>>5, f=t&31); metadata preloaded per-lane,
// broadcast per edge via __shfl; only x row load in the loop (prefetch depth 1).
// GEMM: wave w -> nodes 2w,2w+1; lane o=t&63; uniform ds_read_b128 of H + WT float4.
__global__ __launch_bounds__(256, 5) void fused_bucket(
        const float* __restrict__ x, const float* __restrict__ pseudo,
        const int* __restrict__ eicol, const float* __restrict__ WT,
        const float* __restrict__ bias, const int* __restrict__ cnt,
        const int* __restrict__ ids, float* __restrict__ out) {
    __shared__ float Hs[8 * 800];
    const int t = threadIdx.x;

    float4* L4 = (float4*)Hs;
    for (int i = t; i < 1600; i += 256) L4[i] = make_float4(0.f, 0.f, 0.f, 0.f);
    __syncthreads();

    // ---- accumulate ----
    {
        const int nn = t >> 5;
        const int f = t & 31;
        const int lane = t & 63;
        const int half = lane & 32;                 // base lane of my 32-lane group
        const int n = blockIdx.x * 8 + nn;
        const int num = cnt[n];

        // prologue: per-lane metadata for up to 2 edges
        int c0 = 0, c1 = 0;
        float q0x = 0.f, q0y = 0.f, q1x = 0.f, q1y = 0.f;
        {
            const int base = n * CAP;
            if (f < num) {
                int id = ids[base + f];
                float2 p = ((const float2*)pseudo)[id];
                c0 = eicol[id]; q0x = p.x; q0y = p.y;
            }
            if (32 + f < num) {
                int id = ids[base + 32 + f];
                float2 p = ((const float2*)pseudo)[id];
                c1 = eicol[id]; q1x = p.x; q1y = p.y;
            }
        }

        float* __restrict__ hb = Hs + nn * 800 + f;
        const int m1 = min(num, 32);
        const int m2 = num - 32;                    // may be <= 0

        float xvN = 0.f;
        {
            int cn = __shfl(c0, half, 64);
            if (num > 0) xvN = x[cn * IN_F + f];
        }
        for (int idx = 0; idx < m1; ++idx) {
            float xv = xvN;
            float px = __shfl(q0x, half + idx, 64);
            float py = __shfl(q0y, half + idx, 64);
            if (idx + 1 < m1) {
                int cn = __shfl(c0, half + idx + 1, 64);
                xvN = x[cn * IN_F + f];
            } else if (m2 > 0) {
                int cn = __shfl(c1, half, 64);
                xvN = x[cn * IN_F + f];
            }
            float b[4]; int k[4];
            basis_from(px, py, b, k);
#pragma unroll
            for (int s = 0; s < 4; ++s) hb[k[s] * IN_F] += b[s] * xv;
        }
        for (int idx = 0; idx < m2; ++idx) {
            float xv = xvN;
            float px = __shfl(q1x, half + idx, 64);
            float py = __shfl(q1y, half + idx, 64);
            if (idx + 1 < m2) {
                int cn = __shfl(c1, half + idx + 1, 64);
                xvN = x[cn * IN_F + f];
            }
            float b[4]; int k[4];
            basis_from(px, py, b, k);
#pragma unroll
            for (int s = 0; s < 4; ++s) hb[k[s] * IN_F] += b[s] * xv;
        }
    }
    __syncthreads();

    // ---- GEMM: out[8 x 64] = H[8 x 800] * W[800 x 64] + bias ----
    {
        const int o = t & 63;
        const int wv = t >> 6;                     // 0..3
        const float* __restrict__ h0 = Hs + (2 * wv) * 800;
        const float* __restrict__ h1 = h0 + 800;
        const float4* __restrict__ wt = (const float4*)(WT + o * 800);
        float bo = bias[o];
        float acc0 = bo, acc1 = bo;

        for (int jq = 0; jq < 200; ++jq) {
            float4 wv4 = wt[jq];
            float4 a = *(const float4*)(h0 + jq * 4);
            float4 c = *(const float4*)(h1 + jq * 4);
            acc0 += a.x * wv4.x + a.y * wv4.y + a.z * wv4.z + a.w * wv4.w;
            acc1 += c.x * wv4.x + c.y * wv4.y + c.z * wv4.z + c.w * wv4.w;
        }
        float* op = out + ((size_t)blockIdx.x * 8 + 2 * wv) * 64 + o;
        op[0] = acc0;
        op[64] = acc1;
    }
}

// =================== legacy CSR tier (fallback) ===================

__global__ __launch_bounds__(256) void zero_cnt(int* __restrict__ cnt) {
    int i = blockIdx.x * 256 + threadIdx.x;
    if (i < N_NODES) cnt[i] = 0;
}

__global__ __launch_bounds__(256) void count_edges(const int* __restrict__ ei,
                                                   int* __restrict__ cnt) {
    int e = blockIdx.x * 256 + threadIdx.x;
    atomicAdd(&cnt[ei[e]], 1);
}

__global__ __launch_bounds__(256) void scan_tiles(const int* __restrict__ cnt,
                                                  int* __restrict__ offs,
                                                  int* __restrict__ tsums) {
    __shared__ int s[256];
    int t = threadIdx.x;
    int base = blockIdx.x * 1024 + t * 4;
    int c[4];
#pragma unroll
    for (int m = 0; m < 4; ++m) {
        int i = base + m;
        c[m] = (i < N_NODES) ? cnt[i] : 0;
    }
    int tsum = c[0] + c[1] + c[2] + c[3];
    s[t] = tsum;
    __syncthreads();
    for (int d = 1; d < 256; d <<= 1) {
        int v = (t >= d) ? s[t - d] : 0;
        __syncthreads();
        s[t] += v;
        __syncthreads();
    }
    int run = (t > 0) ? s[t - 1] : 0;
#pragma unroll
    for (int m = 0; m < 4; ++m) {
        int i = base + m;
        if (i < N_NODES) offs[i] = run;
        run += c[m];
    }
    if (t == 255) tsums[blockIdx.x] = s[255];
}

__global__ __launch_bounds__(128) void scan_sums(const int* __restrict__ tsums,
                                                 int* __restrict__ tbase) {
    __shared__ int s[128];
    int t = threadIdx.x;
    int v0 = (t < N_TILES) ? tsums[t] : 0;
    s[t] = v0;
    __syncthreads();
    for (int d = 1; d < 128; d <<= 1) {
        int v = (t >= d) ? s[t - d] : 0;
        __syncthreads();
        s[t] += v;
        __syncthreads();
    }
    tbase[t] = (t > 0) ? s[t - 1] : 0;
}

__global__ __launch_bounds__(256) void finalize_offs(int* __restrict__ offs,
                                                     const int* __restrict__ tbase,
                                                     int* __restrict__ cursor) {
    int i = blockIdx.x * 256 + threadIdx.x;
    if (i < N_NODES) {
        int o = offs[i] + tbase[i >> 10];
        offs[i] = o;
        cursor[i] = o;
    }
}

__global__ __launch_bounds__(256) void fill_csr_ids(const int* __restrict__ ei,
                                                    int* __restrict__ cursor,
                                                    int* __restrict__ payload) {
    int e = blockIdx.x * 256 + threadIdx.x;
    int row = ei[e];
    int pos = atomicAdd(&cursor[row], 1);
    payload[pos] = e;
}

__global__ __launch_bounds__(256, 1) void fused_spline_ids(
        const float* __restrict__ x, const float* __restrict__ pseudo,
        const int* __restrict__ ei, const float* __restrict__ W,
        const float* __restrict__ bias, const int* __restrict__ offs,
        const int* __restrict__ cnt, const int* __restrict__ ids,
        float* __restrict__ out) {
    __shared__ float Hs[16 * 800];
    const int t = threadIdx.x;
    float4* L4 = (float4*)Hs;
    for (int i = t; i < 3200; i += 256) L4[i] = make_float4(0.f, 0.f, 0.f, 0.f);
    __syncthreads();
    {
        const int nn = t >> 4;
        const int fp = t & 15;
        const int n = blockIdx.x * 16 + nn;
        const int start = offs[n];
        const int num = cnt[n];
        float* __restrict__ hb = Hs + nn * 800 + 2 * fp;
        int en; float2 pn, xnxt;
        if (num > 0) {
            en = ids[start];
            pn = *(const float2*)(pseudo + 2 * en);
            int cn = ei[N_EDGES + en];
            xnxt = *(const float2*)(x + (size_t)cn * IN_F + 2 * fp);
        }
        for (int idx = 0; idx < num; ++idx) {
            float2 pc = pn; float2 xv = xnxt;
            if (idx + 1 < num) {
                en = ids[start + idx + 1];
                pn = *(const float2*)(pseudo + 2 * en);
                int cn = ei[N_EDGES + en];
                xnxt = *(const float2*)(x + (size_t)cn * IN_F + 2 * fp);
            }
            float b[4]; int k[4];
            basis_from(pc.x, pc.y, b, k);
#pragma unroll
            for (int s = 0; s < 4; ++s) {
                float2* p = (float2*)(hb + k[s] * IN_F);
                float2 v = *p;
                v.x += b[s] * xv.x;
                v.y += b[s] * xv.y;
                *p = v;
            }
        }
    }
    __syncthreads();
    {
        const int o = t & 63;
        const int w = t >> 6;
        const float* __restrict__ h = Hs + (w * 4) * 800;
        float bo = bias[o];
        float acc0 = bo, acc1 = bo, acc2 = bo, acc3 = bo;
        for (int j = 0; j < 800; j += 4) {
            float4 h0 = *(const float4*)(h + 0 * 800 + j);
            float4 h1 = *(const float4*)(h + 1 * 800 + j);
            float4 h2 = *(const float4*)(h + 2 * 800 + j);
            float4 h3 = *(const float4*)(h + 3 * 800 + j);
            float w0 = W[(j + 0) * 64 + o];
            float w1 = W[(j + 1) * 64 + o];
            float w2 = W[(j + 2) * 64 + o];
            float w3 = W[(j + 3) * 64 + o];
            acc0 += h0.x * w0 + h0.y * w1 + h0.z * w2 + h0.w * w3;
            acc1 += h1.x * w0 + h1.y * w1 + h1.z * w2 + h1.w * w3;
            acc2 += h2.x * w0 + h2.y * w1 + h2.z * w2 + h2.w * w3;
            acc3 += h3.x * w0 + h3.y * w1 + h3.z * w2 + h3.w * w3;
        }
        float* op = out + ((size_t)blockIdx.x * 16 + w * 4) * 64 + o;
        op[0 * 64] = acc0;
        op[1 * 64] = acc1;
        op[2 * 64] = acc2;
        op[3 * 64] = acc3;
    }
}

// =================== direct tier (tiny ws) ===================

__global__ __launch_bounds__(256) void bias_init(const float* __restrict__ bias,
                                                 float* __restrict__ out) {
    int idx = blockIdx.x * 256 + threadIdx.x;
    if (idx < N_NODES * OUT_F) out[idx] = bias[idx & 63];
}

__global__ __launch_bounds__(256) void spline_direct(
        const float* __restrict__ x, const float* __restrict__ pseudo,
        const int* __restrict__ ei, const float* __restrict__ W,
        float* __restrict__ out) {
    int gtid = blockIdx.x * 256 + threadIdx.x;
    int e = gtid >> 6;
    int lane = threadIdx.x & 63;
    if (e >= N_EDGES) return;
    int row = ei[e];
    int col = ei[N_EDGES + e];
    float b[4]; int k[4];
    basis_from(pseudo[e * 2 + 0], pseudo[e * 2 + 1], b, k);
    float xv = x[col * IN_F + (lane & 31)];
    float acc = 0.0f;
#pragma unroll
    for (int s = 0; s < 4; ++s) {
        const float* __restrict__ Wk = W + k[s] * (IN_F * OUT_F);
        float part = 0.0f;
#pragma unroll
        for (int i = 0; i < IN_F; ++i) {
            float xi = __shfl(xv, i, 64);
            part += xi * Wk[i * OUT_F + lane];
        }
        acc += b[s] * part;
    }
    atomicAdd(&out[row * OUT_F + lane], acc);
}

extern "C" void kernel_launch(void* const* d_in, const int* in_sizes, int n_in,
                              void* d_out, int out_size, void* d_ws, size_t ws_size,
                              hipStream_t stream) {
    const float* features = (const float*)d_in[0];   // [100000, 32]
    const float* pseudo   = (const float*)d_in[1];   // [1600000, 2]
    const int*   eidx     = (const int*)d_in[2];     // [2, 1600000]
    const float* weight   = (const float*)d_in[3];   // [5,5,32,64] -> [800,64]
    const float* bias     = (const float*)d_in[4];   // [64]
    float* out = (float*)d_out;

    char* ws = (char*)d_ws;

    if (ws_size >= WSB_NEED) {
        int*   cnt = (int*)(ws + WSB_CNT);
        float* WT  = (float*)(ws + WSB_WT);
        int*   ids = (int*)(ws + WSB_IDS);
        hipMemsetAsync(cnt, 0, N_NODES * sizeof(int), stream);
        transpose_w<<<200, 256, 0, stream>>>(weight, WT);
        fill_bucket<<<N_EDGES / 256, 256, 0, stream>>>(eidx, cnt, ids);
        fused_bucket<<<N_NODES / 8, 256, 0, stream>>>(
            features, pseudo, eidx + N_EDGES, WT, bias, cnt, ids, out);
    } else if (ws_size >= (size_t)WS_PAYLOAD + (size_t)N_EDGES * 4) {
        int* cnt    = (int*)(ws + WS_CNT);
        int* offs   = (int*)(ws + WS_OFFS);
        int* cursor = (int*)(ws + WS_CURSOR);
        int* tsums  = (int*)(ws + WS_TSUMS);
        int* tbase  = (int*)(ws + WS_TBASE);
        int* ids    = (int*)(ws + WS_PAYLOAD);
        const int nodeBlocks = (N_NODES + 255) / 256;
        zero_cnt<<<nodeBlocks, 256, 0, stream>>>(cnt);
        count_edges<<<N_EDGES / 256, 256, 0, stream>>>(eidx, cnt);
        scan_tiles<<<N_TILES, 256, 0, stream>>>(cnt, offs, tsums);
        scan_sums<<<1, 128, 0, stream>>>(tsums, tbase);
        finalize_offs<<<nodeBlocks, 256, 0, stream>>>(offs, tbase, cursor);
        fill_csr_ids<<<N_EDGES / 256, 256, 0, stream>>>(eidx, cursor, ids);
        fused_spline_ids<<<N_NODES / 16, 256, 0, stream>>>(
            features, pseudo, eidx, weight, bias, offs, cnt, ids, out);
    } else {
        int blocks = (N_NODES * OUT_F + 255) / 256;
        bias_init<<<blocks, 256, 0, stream>>>(bias, out);
        long long total = (long long)N_EDGES * 64;
        spline_direct<<<(int)((total + 255) / 256), 256, 0, stream>>>(
            features, pseudo, eidx, weight, out);
    }
}

// Round 4
// 532.329 us; speedup vs baseline: 2.8405x; 2.8405x over previous
//
#include <hip/hip_runtime.h>

#define N_NODES 100000
#define N_EDGES 1600000
#define IN_F 32
#define OUT_F 64
#define K_TOTAL 25          // 5x5
#define N_TILES 98          // ceil(100000/1024)

// ---- workspace layout (bytes) ----
// cnt    : int[100000]    @ 0
// offs   : int[100001]    @ 400000   (ends 800004, pad)
// cursor : int[100000]    @ 800016
// WT4    : float[51200]   @ 1200032  (16B aligned; [200][64] float4)
// rec8   : uint2[1600000] @ 1404832  (16B aligned)
#define WS_CNT    0
#define WS_OFFS   400000
#define WS_CURSOR 800016
#define WS_WT4    1200032
#define WS_REC    1404832
#define WS_NEED   (1404832 + (size_t)N_EDGES * 8)   // 14,204,832

// =================== build kernels ===================

__global__ __launch_bounds__(256) void transpose_w4(const float* __restrict__ W,
                                                    float* __restrict__ WT4f) {
    int idx = blockIdx.x * 256 + threadIdx.x;      // grid covers 51200 exactly
    int j = idx >> 6, o = idx & 63;
    // dst: float4 index (jq*64 + o), component j&3
    WT4f[((j >> 2) * 64 + o) * 4 + (j & 3)] = W[idx];
}

__global__ __launch_bounds__(256) void count_edges(const int* __restrict__ ei,
                                                   int* __restrict__ cnt) {
    int e = blockIdx.x * 256 + threadIdx.x;        // grid covers N_EDGES exactly
    atomicAdd(&cnt[ei[e]], 1);
}

// single-kernel exclusive scan: block b brute-force sums cnt[0..b*1024) for its base,
// then scans its own 1024-tile. No inter-block dependencies.
__global__ __launch_bounds__(256) void scan_brute(const int* __restrict__ cnt,
                                                  int* __restrict__ offs,
                                                  int* __restrict__ cursor) {
    __shared__ int s[256];
    const int b = blockIdx.x, t = threadIdx.x;
    int part = 0;
    for (int i = t; i < b * 1024; i += 256) part += cnt[i];
    s[t] = part;
    __syncthreads();
    for (int d = 128; d > 0; d >>= 1) {
        if (t < d) s[t] += s[t + d];
        __syncthreads();
    }
    const int base = s[0];
    __syncthreads();

    int idx0 = b * 1024 + t * 4;
    int c[4];
#pragma unroll
    for (int m = 0; m < 4; ++m) {
        int i = idx0 + m;
        c[m] = (i < N_NODES) ? cnt[i] : 0;
    }
    int tsum = c[0] + c[1] + c[2] + c[3];
    s[t] = tsum;
    __syncthreads();
    for (int d = 1; d < 256; d <<= 1) {
        int v = (t >= d) ? s[t - d] : 0;
        __syncthreads();
        s[t] += v;
        __syncthreads();
    }
    int ex = base + ((t > 0) ? s[t - 1] : 0);
#pragma unroll
    for (int m = 0; m < 4; ++m) {
        int i = idx0 + m;
        if (i < N_NODES) {
            offs[i] = ex;
            cursor[i] = ex;
            ex += c[m];
            if (i == N_NODES - 1) offs[N_NODES] = ex;
        }
    }
}

// per-edge 8B record in CSR position: {col | kbase<<20, f0_unorm16 | f1_unorm16<<16}
__global__ __launch_bounds__(256) void fill_rec(const int* __restrict__ ei,
                                                const float* __restrict__ pseudo,
                                                int* __restrict__ cursor,
                                                uint2* __restrict__ rec) {
    int e = blockIdx.x * 256 + threadIdx.x;        // grid covers N_EDGES exactly
    int row = ei[e];
    int col = ei[N_EDGES + e];
    float2 p = ((const float2*)pseudo)[e];
    float v0 = p.x * 4.0f, v1 = p.y * 4.0f;
    int i0 = min((int)v0, 3);
    int i1 = min((int)v1, 3);
    float f0 = v0 - (float)i0;
    float f1 = v1 - (float)i1;
    unsigned u0 = (unsigned)(f0 * 65535.0f + 0.5f);
    unsigned u1 = (unsigned)(f1 * 65535.0f + 0.5f);
    uint2 r;
    r.x = (unsigned)col | ((unsigned)(i0 * 5 + i1) << 20);
    r.y = u0 | (u1 << 16);
    int pos = atomicAdd(&cursor[row], 1);
    rec[pos] = r;
}

// =================== fused accumulate + GEMM ===================
// 256 threads, 16 nodes/block. LDS H[16][800] = 51.2 KB -> 3 blocks/CU.
// Accumulate: 16 threads/node (nn=t>>4, fp=t&15, float2 per thread).
//   Records prefetched 4-deep, x rows 2-deep (2-level dependent chain).
// GEMM: wave w -> nodes 4w..4w+3; lane o; coalesced WT4 float4; v2f accumulators.
typedef float v2f __attribute__((ext_vector_type(2)));

__global__ __launch_bounds__(256, 3) void fused4(
        const float* __restrict__ x, const float* __restrict__ WT4f,
        const float* __restrict__ bias, const int* __restrict__ offs,
        const uint2* __restrict__ recs, float* __restrict__ out) {
    __shared__ float Hs[16 * 800];
    const int t = threadIdx.x;

    float4* L4 = (float4*)Hs;
    for (int i = t; i < 3200; i += 256) L4[i] = make_float4(0.f, 0.f, 0.f, 0.f);
    __syncthreads();

    // ---- accumulate ----
    {
        const int nn = t >> 4;
        const int fp = t & 15;
        const int n = blockIdx.x * 16 + nn;
        const int start = offs[n];
        const int num = offs[n + 1] - start;
        float* __restrict__ hb = Hs + nn * 800 + 2 * fp;

        if (num > 0) {
            const uint2* __restrict__ rp = recs + start;
            const int last = num - 1;
            uint2 r0 = rp[0];
            uint2 r1 = rp[min(1, last)];
            uint2 r2 = rp[min(2, last)];
            uint2 r3 = rp[min(3, last)];
            float2 xv0 = *(const float2*)(x + (size_t)(r0.x & 0xFFFFF) * IN_F + 2 * fp);
            float2 xv1 = *(const float2*)(x + (size_t)(r1.x & 0xFFFFF) * IN_F + 2 * fp);

            for (int i = 0; i < num; ++i) {
                uint2 r4 = rp[min(i + 4, last)];
                float2 xn = *(const float2*)(x + (size_t)(r2.x & 0xFFFFF) * IN_F + 2 * fp);

                float f0 = (float)(r0.y & 0xFFFF) * (1.0f / 65535.0f);
                float f1 = (float)(r0.y >> 16) * (1.0f / 65535.0f);
                float a0 = 1.0f - f0, a1 = 1.0f - f1;
                float b0 = a0 * a1, b1 = a0 * f1, b2 = f0 * a1, b3 = f0 * f1;
                float* __restrict__ p = hb + ((r0.x >> 20) << 5);   // kbase*32 floats

                float2 h;
                h = *(float2*)(p);       h.x += b0 * xv0.x; h.y += b0 * xv0.y; *(float2*)(p)       = h;
                h = *(float2*)(p + 32);  h.x += b1 * xv0.x; h.y += b1 * xv0.y; *(float2*)(p + 32)  = h;
                h = *(float2*)(p + 160); h.x += b2 * xv0.x; h.y += b2 * xv0.y; *(float2*)(p + 160) = h;
                h = *(float2*)(p + 192); h.x += b3 * xv0.x; h.y += b3 * xv0.y; *(float2*)(p + 192) = h;

                r0 = r1; r1 = r2; r2 = r3; r3 = r4;
                xv0 = xv1; xv1 = xn;
            }
        }
    }
    __syncthreads();

    // ---- GEMM: out[16 x 64] = H[16 x 800] * W[800 x 64] + bias ----
    {
        const int o = t & 63;
        const int wv = t >> 6;
        const float4* __restrict__ wt = ((const float4*)WT4f) + o;
        const float* __restrict__ h0 = Hs + (wv * 4) * 800;

        v2f acc[4][2];
#pragma unroll
        for (int nd = 0; nd < 4; ++nd) { acc[nd][0] = (v2f)0.0f; acc[nd][1] = (v2f)0.0f; }

        for (int jq = 0; jq < 200; ++jq) {
            float4 w4 = wt[jq * 64];
            v2f wa = {w4.x, w4.y}, wb = {w4.z, w4.w};
#pragma unroll
            for (int nd = 0; nd < 4; ++nd) {
                float4 h4 = *(const float4*)(h0 + nd * 800 + jq * 4);
                v2f ha = {h4.x, h4.y}, hb2 = {h4.z, h4.w};
                acc[nd][0] += ha * wa;
                acc[nd][1] += hb2 * wb;
            }
        }
        float bo = bias[o];
        float* __restrict__ op = out + ((size_t)blockIdx.x * 16 + wv * 4) * 64 + o;
#pragma unroll
        for (int nd = 0; nd < 4; ++nd) {
            op[nd * 64] = bo + acc[nd][0].x + acc[nd][0].y + acc[nd][1].x + acc[nd][1].y;
        }
    }
}

// =================== direct fallback (tiny ws) ===================

__device__ __forceinline__ void basis_from(float p0, float p1, float b[4], int k[4]) {
    float v0 = p0 * 4.0f, v1 = p1 * 4.0f;
    int i0 = min(max((int)floorf(v0), 0), 3);
    int i1 = min(max((int)floorf(v1), 0), 3);
    float f0 = v0 - (float)i0, f1 = v1 - (float)i1;
    float a00 = 1.0f - f0, a10 = 1.0f - f1;
    b[0] = a00 * a10; k[0] = i0 * 5 + i1;
    b[1] = a00 * f1;  k[1] = i0 * 5 + i1 + 1;
    b[2] = f0 * a10;  k[2] = (i0 + 1) * 5 + i1;
    b[3] = f0 * f1;   k[3] = (i0 + 1) * 5 + i1 + 1;
}

__global__ __launch_bounds__(256) void bias_init(const float* __restrict__ bias,
                                                 float* __restrict__ out) {
    int idx = blockIdx.x * 256 + threadIdx.x;
    if (idx < N_NODES * OUT_F) out[idx] = bias[idx & 63];
}

__global__ __launch_bounds__(256) void spline_direct(
        const float* __restrict__ x, const float* __restrict__ pseudo,
        const int* __restrict__ ei, const float* __restrict__ W,
        float* __restrict__ out) {
    int gtid = blockIdx.x * 256 + threadIdx.x;
    int e = gtid >> 6;
    int lane = threadIdx.x & 63;
    if (e >= N_EDGES) return;
    int row = ei[e];
    int col = ei[N_EDGES + e];
    float b[4]; int k[4];
    basis_from(pseudo[e * 2 + 0], pseudo[e * 2 + 1], b, k);
    float xv = x[col * IN_F + (lane & 31)];
    float acc = 0.0f;
#pragma unroll
    for (int s = 0; s < 4; ++s) {
        const float* __restrict__ Wk = W + k[s] * (IN_F * OUT_F);
        float part = 0.0f;
#pragma unroll
        for (int i = 0; i < IN_F; ++i) {
            float xi = __shfl(xv, i, 64);
            part += xi * Wk[i * OUT_F + lane];
        }
        acc += b[s] * part;
    }
    atomicAdd(&out[row * OUT_F + lane], acc);
}

extern "C" void kernel_launch(void* const* d_in, const int* in_sizes, int n_in,
                              void* d_out, int out_size, void* d_ws, size_t ws_size,
                              hipStream_t stream) {
    const float* features = (const float*)d_in[0];   // [100000, 32]
    const float* pseudo   = (const float*)d_in[1];   // [1600000, 2]
    const int*   eidx     = (const int*)d_in[2];     // [2, 1600000]
    const float* weight   = (const float*)d_in[3];   // [5,5,32,64] -> [800,64]
    const float* bias     = (const float*)d_in[4];   // [64]
    float* out = (float*)d_out;

    char* ws = (char*)d_ws;

    if (ws_size >= WS_NEED) {
        int*   cnt    = (int*)(ws + WS_CNT);
        int*   offs   = (int*)(ws + WS_OFFS);
        int*   cursor = (int*)(ws + WS_CURSOR);
        float* WT4f   = (float*)(ws + WS_WT4);
        uint2* rec    = (uint2*)(ws + WS_REC);

        hipMemsetAsync(cnt, 0, N_NODES * sizeof(int), stream);
        transpose_w4<<<200, 256, 0, stream>>>(weight, WT4f);
        count_edges<<<N_EDGES / 256, 256, 0, stream>>>(eidx, cnt);
        scan_brute<<<N_TILES, 256, 0, stream>>>(cnt, offs, cursor);
        fill_rec<<<N_EDGES / 256, 256, 0, stream>>>(eidx, pseudo, cursor, rec);
        fused4<<<N_NODES / 16, 256, 0, stream>>>(features, WT4f, bias, offs, rec, out);
    } else {
        int blocks = (N_NODES * OUT_F + 255) / 256;
        bias_init<<<blocks, 256, 0, stream>>>(bias, out);
        long long total = (long long)N_EDGES * 64;
        spline_direct<<<(int)((total + 255) / 256), 256, 0, stream>>>(
            features, pseudo, eidx, weight, out);
    }
}

// Round 7
// 448.024 us; speedup vs baseline: 3.3750x; 1.1882x over previous
//
#include <hip/hip_runtime.h>

#define N_NODES 100000
#define N_EDGES 1600000
#define IN_F 32
#define OUT_F 64
#define K_TOTAL 25          // 5x5
#define CAP 31              // bucket capacity; overflow exact via ovf list (~30 edges expected)
#define OVF_CAP 8192

// ---- workspace layout (bytes) ----
// cnt    : int[100000]      @ 0         (400000)
// ovfcnt : int              @ 400000
// WT4    : float[51200]     @ 400064    (204800; 16B aligned; [200][64] float4)
// ovf    : uint4[8192]      @ 604864    (131072; 16B aligned)
// recs   : uint2[100000*31] @ 735936    (24800000; 16B aligned)
#define WS_CNT    0
#define WS_OVFCNT 400000
#define WS_WT4    400064
#define WS_OVF    604864
#define WS_REC    735936
#define WS_NEED   (735936 + (size_t)N_NODES * CAP * 8)   // 25,535,936 (< proven 26.2 MB)

typedef float v2f __attribute__((ext_vector_type(2)));

// =================== build kernels ===================

// (round-4 validated) W[j=800][o=64] -> WT4 [jq=200][o=64] float4 over j%4
__global__ __launch_bounds__(256) void transpose_w4(const float* __restrict__ W,
                                                    float* __restrict__ WT4f) {
    int idx = blockIdx.x * 256 + threadIdx.x;      // grid covers 51200 exactly
    int j = idx >> 6, o = idx & 63;
    WT4f[((j >> 2) * 64 + o) * 4 + (j & 3)] = W[idx];
}

// single atomic pass: rec {col | kbase<<20, f0u16 | f1u16<<16} -> bucket; overflow -> list
__global__ __launch_bounds__(256) void fill_bucket(const int* __restrict__ ei,
                                                   const float* __restrict__ pseudo,
                                                   int* __restrict__ cnt,
                                                   uint2* __restrict__ recs,
                                                   uint4* __restrict__ ovf,
                                                   int* __restrict__ ovfcnt) {
    int e = blockIdx.x * 256 + threadIdx.x;        // grid covers N_EDGES exactly
    int row = ei[e];
    int col = ei[N_EDGES + e];
    float2 p = ((const float2*)pseudo)[e];
    float v0 = p.x * 4.0f, v1 = p.y * 4.0f;
    int i0 = min((int)v0, 3);
    int i1 = min((int)v1, 3);
    float f0 = v0 - (float)i0;
    float f1 = v1 - (float)i1;
    unsigned u0 = (unsigned)(f0 * 65535.0f + 0.5f);
    unsigned u1 = (unsigned)(f1 * 65535.0f + 0.5f);
    unsigned rx = (unsigned)col | ((unsigned)(i0 * 5 + i1) << 20);
    unsigned ry = u0 | (u1 << 16);
    int pos = atomicAdd(&cnt[row], 1);
    if (pos < CAP) {
        recs[(size_t)row * CAP + pos] = (uint2){rx, ry};
    } else {
        int j = atomicAdd(ovfcnt, 1);
        if (j < OVF_CAP) ovf[j] = (uint4){(unsigned)row, rx, ry, 0u};
    }
}

// =================== fused accumulate + GEMM (round-4 validated kernel) ===================
// 256 threads, 16 nodes/block. LDS H[16][800] = 51.2 KB -> 3 blocks/CU.
// Accumulate: 16 threads/node (nn=t>>4, fp=t&15, float2/thread); recs prefetched
// 4-deep, x rows 2-deep. GEMM: wave wv -> nodes 4wv..4wv+3; coalesced WT4 float4.
__global__ __launch_bounds__(256, 3) void fused4(
        const float* __restrict__ x, const float* __restrict__ WT4f,
        const float* __restrict__ bias, const int* __restrict__ cnt,
        const uint2* __restrict__ recs, float* __restrict__ out) {
    __shared__ float Hs[16 * 800];
    const int t = threadIdx.x;

    float4* L4 = (float4*)Hs;
    for (int i = t; i < 3200; i += 256) L4[i] = make_float4(0.f, 0.f, 0.f, 0.f);
    __syncthreads();

    // ---- accumulate ----
    {
        const int nn = t >> 4;
        const int fp = t & 15;
        const int n = blockIdx.x * 16 + nn;
        const int num = min(cnt[n], CAP);
        float* __restrict__ hb = Hs + nn * 800 + 2 * fp;

        if (num > 0) {
            const uint2* __restrict__ rp = recs + (size_t)n * CAP;
            const int last = num - 1;
            uint2 r0 = rp[0];
            uint2 r1 = rp[min(1, last)];
            uint2 r2 = rp[min(2, last)];
            uint2 r3 = rp[min(3, last)];
            float2 xv0 = *(const float2*)(x + (size_t)(r0.x & 0xFFFFF) * IN_F + 2 * fp);
            float2 xv1 = *(const float2*)(x + (size_t)(r1.x & 0xFFFFF) * IN_F + 2 * fp);

            for (int i = 0; i < num; ++i) {
                uint2 r4 = rp[min(i + 4, last)];
                float2 xn = *(const float2*)(x + (size_t)(r2.x & 0xFFFFF) * IN_F + 2 * fp);

                float f0 = (float)(r0.y & 0xFFFF) * (1.0f / 65535.0f);
                float f1 = (float)(r0.y >> 16) * (1.0f / 65535.0f);
                float a0 = 1.0f - f0, a1 = 1.0f - f1;
                float b0 = a0 * a1, b1 = a0 * f1, b2 = f0 * a1, b3 = f0 * f1;
                float* __restrict__ p = hb + ((r0.x >> 20) << 5);   // kbase*32 floats

                float2 h;
                h = *(float2*)(p);       h.x += b0 * xv0.x; h.y += b0 * xv0.y; *(float2*)(p)       = h;
                h = *(float2*)(p + 32);  h.x += b1 * xv0.x; h.y += b1 * xv0.y; *(float2*)(p + 32)  = h;
                h = *(float2*)(p + 160); h.x += b2 * xv0.x; h.y += b2 * xv0.y; *(float2*)(p + 160) = h;
                h = *(float2*)(p + 192); h.x += b3 * xv0.x; h.y += b3 * xv0.y; *(float2*)(p + 192) = h;

                r0 = r1; r1 = r2; r2 = r3; r3 = r4;
                xv0 = xv1; xv1 = xn;
            }
        }
    }
    __syncthreads();

    // ---- GEMM: out[16 x 64] = H[16 x 800] * W[800 x 64] + bias ----
    {
        const int o = t & 63;
        const int wv = t >> 6;
        const float4* __restrict__ wt = ((const float4*)WT4f) + o;
        const float* __restrict__ h0 = Hs + (wv * 4) * 800;

        v2f acc[4][2];
#pragma unroll
        for (int nd = 0; nd < 4; ++nd) { acc[nd][0] = (v2f)0.0f; acc[nd][1] = (v2f)0.0f; }

        for (int jq = 0; jq < 200; ++jq) {
            float4 w4 = wt[jq * 64];
            v2f wa = {w4.x, w4.y}, wb = {w4.z, w4.w};
#pragma unroll
            for (int nd = 0; nd < 4; ++nd) {
                float4 h4 = *(const float4*)(h0 + nd * 800 + jq * 4);
                v2f ha = {h4.x, h4.y}, hb2 = {h4.z, h4.w};
                acc[nd][0] += ha * wa;
                acc[nd][1] += hb2 * wb;
            }
        }
        float bo = bias[o];
        float* __restrict__ op = out + ((size_t)blockIdx.x * 16 + wv * 4) * 64 + o;
#pragma unroll
        for (int nd = 0; nd < 4; ++nd) {
            op[nd * 64] = bo + acc[nd][0].x + acc[nd][0].y + acc[nd][1].x + acc[nd][1].y;
        }
    }
}

// exact fix-up for bucket-overflow edges (expected ~tens); atomic-adds after fused4
__global__ __launch_bounds__(256) void ovf_fix(const float* __restrict__ x,
                                               const float* __restrict__ W,
                                               const uint4* __restrict__ ovf,
                                               const int* __restrict__ ovfcnt,
                                               float* __restrict__ out) {
    const int lane = threadIdx.x & 63;
    const int wv = threadIdx.x >> 6;
    int m = min(*ovfcnt, OVF_CAP);
    for (int idx = wv; idx < m; idx += 4) {
        uint4 v = ovf[idx];
        int row = (int)v.x;
        int col = (int)(v.y & 0xFFFFF);
        int kbase = (int)(v.y >> 20);
        float f0 = (float)(v.z & 0xFFFF) * (1.0f / 65535.0f);
        float f1 = (float)(v.z >> 16) * (1.0f / 65535.0f);
        float a0 = 1.0f - f0, a1 = 1.0f - f1;
        float bb[4] = {a0 * a1, a0 * f1, f0 * a1, f0 * f1};
        const int dk[4] = {0, 1, 5, 6};
        float acc = 0.0f;
#pragma unroll
        for (int s = 0; s < 4; ++s) {
            const float* __restrict__ Wk = W + (size_t)(kbase + dk[s]) * (IN_F * OUT_F);
            float part = 0.0f;
            for (int i = 0; i < IN_F; ++i)
                part += x[(size_t)col * IN_F + i] * Wk[i * OUT_F + lane];
            acc += bb[s] * part;
        }
        atomicAdd(&out[(size_t)row * OUT_F + lane], acc);
    }
}

// =================== direct fallback (tiny ws; validated round 1) ===================

__device__ __forceinline__ void basis_from(float p0, float p1, float b[4], int k[4]) {
    float v0 = p0 * 4.0f, v1 = p1 * 4.0f;
    int i0 = min(max((int)floorf(v0), 0), 3);
    int i1 = min(max((int)floorf(v1), 0), 3);
    float f0 = v0 - (float)i0, f1 = v1 - (float)i1;
    float a00 = 1.0f - f0, a10 = 1.0f - f1;
    b[0] = a00 * a10; k[0] = i0 * 5 + i1;
    b[1] = a00 * f1;  k[1] = i0 * 5 + i1 + 1;
    b[2] = f0 * a10;  k[2] = (i0 + 1) * 5 + i1;
    b[3] = f0 * f1;   k[3] = (i0 + 1) * 5 + i1 + 1;
}

__global__ __launch_bounds__(256) void bias_init(const float* __restrict__ bias,
                                                 float* __restrict__ out) {
    int idx = blockIdx.x * 256 + threadIdx.x;
    if (idx < N_NODES * OUT_F) out[idx] = bias[idx & 63];
}

__global__ __launch_bounds__(256) void spline_direct(
        const float* __restrict__ x, const float* __restrict__ pseudo,
        const int* __restrict__ ei, const float* __restrict__ W,
        float* __restrict__ out) {
    int gtid = blockIdx.x * 256 + threadIdx.x;
    int e = gtid >> 6;
    int lane = threadIdx.x & 63;
    if (e >= N_EDGES) return;
    int row = ei[e];
    int col = ei[N_EDGES + e];
    float b[4]; int k[4];
    basis_from(pseudo[e * 2 + 0], pseudo[e * 2 + 1], b, k);
    float xv = x[col * IN_F + (lane & 31)];
    float acc = 0.0f;
#pragma unroll
    for (int s = 0; s < 4; ++s) {
        const float* __restrict__ Wk = W + k[s] * (IN_F * OUT_F);
        float part = 0.0f;
#pragma unroll
        for (int i = 0; i < IN_F; ++i) {
            float xi = __shfl(xv, i, 64);
            part += xi * Wk[i * OUT_F + lane];
        }
        acc += b[s] * part;
    }
    atomicAdd(&out[row * OUT_F + lane], acc);
}

extern "C" void kernel_launch(void* const* d_in, const int* in_sizes, int n_in,
                              void* d_out, int out_size, void* d_ws, size_t ws_size,
                              hipStream_t stream) {
    const float* features = (const float*)d_in[0];   // [100000, 32]
    const float* pseudo   = (const float*)d_in[1];   // [1600000, 2]
    const int*   eidx     = (const int*)d_in[2];     // [2, 1600000]
    const float* weight   = (const float*)d_in[3];   // [5,5,32,64] -> [800,64]
    const float* bias     = (const float*)d_in[4];   // [64]
    float* out = (float*)d_out;

    char* ws = (char*)d_ws;

    if (ws_size >= WS_NEED) {
        int*   cnt    = (int*)(ws + WS_CNT);
        int*   ovfcnt = (int*)(ws + WS_OVFCNT);
        float* WT4f   = (float*)(ws + WS_WT4);
        uint4* ovf    = (uint4*)(ws + WS_OVF);
        uint2* recs   = (uint2*)(ws + WS_REC);

        hipMemsetAsync(cnt, 0, 400016, stream);      // cnt + ovfcnt
        transpose_w4<<<200, 256, 0, stream>>>(weight, WT4f);
        fill_bucket<<<N_EDGES / 256, 256, 0, stream>>>(eidx, pseudo, cnt, recs, ovf, ovfcnt);
        fused4<<<N_NODES / 16, 256, 0, stream>>>(features, WT4f, bias, cnt, recs, out);
        ovf_fix<<<1, 256, 0, stream>>>(features, weight, ovf, ovfcnt, out);
    } else {
        int blocks = (N_NODES * OUT_F + 255) / 256;
        bias_init<<<blocks, 256, 0, stream>>>(bias, out);
        long long total = (long long)N_EDGES * 64;
        spline_direct<<<(int)((total + 255) / 256), 256, 0, stream>>>(
            features, pseudo, eidx, weight, out);
    }
}